// Round 7
// baseline (1039.022 us; speedup 1.0000x reference)
//
#include <hip/hip_runtime.h>
#include <math.h>

#define H    512
#define TH3  1536
#define GRID 224

// ---------------- workspace layout (float offsets), P=3 parities ----------------
#define WS_STATE(l,p) ((size_t)((l)*3+(p)) * 8192)          // 0 .. 73728
#define WS_A1(p)      ((size_t)73728 + (size_t)(p)*8192)    // 73728 .. 98304
#define WS_ATOMS      ((size_t)98304)                        // 98304 .. 884736
#define WS_E          ((size_t)884736)                       // e_i/e_j buffers
// flags u32[256] at WS_E during k_gru; k_eij overwrites the region afterwards.

__device__ __forceinline__ float sigm_(float x) { return 1.0f / (1.0f + expf(-x)); }

// ---- coherent (L3-point) memory helpers: bypass L1+L2 via sc0 sc1 ----
__device__ __forceinline__ void ld_coh4(const float* p0, const float* p1,
                                        const float* p2, const float* p3,
                                        float4& a, float4& b, float4& c, float4& d)
{
    asm volatile(
        "global_load_dwordx4 %0, %4, off sc0 sc1\n\t"
        "global_load_dwordx4 %1, %5, off sc0 sc1\n\t"
        "global_load_dwordx4 %2, %6, off sc0 sc1\n\t"
        "global_load_dwordx4 %3, %7, off sc0 sc1\n\t"
        "s_waitcnt vmcnt(0)"
        : "=&v"(a), "=&v"(b), "=&v"(c), "=&v"(d)
        : "v"(p0), "v"(p1), "v"(p2), "v"(p3)
        : "memory");
}

__device__ __forceinline__ void ld_coh8(const float* p0, const float* p1,
                                        const float* p2, const float* p3,
                                        const float* p4, const float* p5,
                                        const float* p6, const float* p7,
                                        float4& a, float4& b, float4& c, float4& d,
                                        float4& e, float4& f, float4& g, float4& h)
{
    asm volatile(
        "global_load_dwordx4 %0, %8, off sc0 sc1\n\t"
        "global_load_dwordx4 %1, %9, off sc0 sc1\n\t"
        "global_load_dwordx4 %2, %10, off sc0 sc1\n\t"
        "global_load_dwordx4 %3, %11, off sc0 sc1\n\t"
        "global_load_dwordx4 %4, %12, off sc0 sc1\n\t"
        "global_load_dwordx4 %5, %13, off sc0 sc1\n\t"
        "global_load_dwordx4 %6, %14, off sc0 sc1\n\t"
        "global_load_dwordx4 %7, %15, off sc0 sc1\n\t"
        "s_waitcnt vmcnt(0)"
        : "=&v"(a), "=&v"(b), "=&v"(c), "=&v"(d),
          "=&v"(e), "=&v"(f), "=&v"(g), "=&v"(h)
        : "v"(p0), "v"(p1), "v"(p2), "v"(p3),
          "v"(p4), "v"(p5), "v"(p6), "v"(p7)
        : "memory");
}

__device__ __forceinline__ void st_coh1(float* p, float v) {
    asm volatile("global_store_dword %0, %1, off sc0 sc1" :: "v"(p), "v"(v) : "memory");
}

__device__ __forceinline__ void ld_coh_u32x3(const unsigned* p0, const unsigned* p1,
                                             const unsigned* p2,
                                             unsigned& a, unsigned& b, unsigned& c)
{
    asm volatile(
        "global_load_dword %0, %3, off sc0 sc1\n\t"
        "global_load_dword %1, %4, off sc0 sc1\n\t"
        "global_load_dword %2, %5, off sc0 sc1\n\t"
        "s_waitcnt vmcnt(0)"
        : "=&v"(a), "=&v"(b), "=&v"(c)
        : "v"(p0), "v"(p1), "v"(p2)
        : "memory");
}

__device__ __forceinline__ void st_coh_u32(unsigned* p, unsigned v) {
    asm volatile("global_store_dword %0, %1, off sc0 sc1" :: "v"(p), "v"(v) : "memory");
}

__device__ __forceinline__ void vm_drain() {
    asm volatile("s_waitcnt vmcnt(0)" ::: "memory");
}

// ---- cross-lane helpers: DPP (VALU) for xor1/xor2/xor8, ds_swizzle for xor4/xor16 ----
template<int CTRL>
__device__ __forceinline__ float dppmov(float v) {
    return __int_as_float(__builtin_amdgcn_update_dpp(
        0, __float_as_int(v), CTRL, 0xF, 0xF, true));
}
#define DPP_XOR1 0xB1   // quad_perm(1,0,3,2)
#define DPP_XOR2 0x4E   // quad_perm(2,3,0,1)
#define DPP_XOR8 0x128  // row_ror:8  (== xor8 within 16)

template<int PAT>
__device__ __forceinline__ float swzf(float v) {
    return __int_as_float(__builtin_amdgcn_ds_swizzle(__float_as_int(v), PAT));
}
#define SWZ_XOR4  0x101F
#define SWZ_XOR16 0x401F

// ---------------- h_init = z @ W_l2h + b_l2h + flag zeroing ----------------
// lane mapping: jl = t&15 (j fast -> coalesced W reads), b = t>>4.
extern "C" __global__ __launch_bounds__(256)
void k_init(const float* __restrict__ z, const float* __restrict__ Wl2h,
            const float* __restrict__ bl2h, float* __restrict__ ws)
{
    if (blockIdx.x == 0)
        ((unsigned*)(ws + WS_E))[threadIdx.x] = 0u;   // flags[0..255]
    const int t  = threadIdx.x;
    const int jl = t & 15, b = t >> 4;
    const int j  = blockIdx.x * 16 + jl;
    float acc = 0.f;
    #pragma unroll 4
    for (int k = 0; k < H; ++k)
        acc += z[b * H + k] * Wl2h[(size_t)k * H + j];
    acc += bl2h[j];
    #pragma unroll
    for (int l = 0; l < 3; ++l)
        #pragma unroll
        for (int p = 0; p < 3; ++p)
            ws[WS_STATE(l, p) + j * 16 + b] = acc;
}

// ---------------- persistent pipelined GRU + MLP decoder ----------------
// blocks: [0,32)=L0 (16 cols), [32,96)=L1 (8 cols), [96,160)=L2 (8),
//         [160,192)=A1 (16), [192,224)=LG (16).  512 threads, dataflow sync.
// P=3 parities: slot s writes parity s%3, reads parity (s+2)%3.
// poll (single wave, batched): producers need flag>=s, anti-deps need flag>=s-1.
__global__ __launch_bounds__(512, 2)
void k_gru(const float* __restrict__ W_ih, const float* __restrict__ W_hh,
           const float* __restrict__ b_ih, const float* __restrict__ b_hh,
           const float* __restrict__ Wa1,  const float* __restrict__ ba1,
           const float* __restrict__ Wa2,  const float* __restrict__ ba2,
           float* __restrict__ ws)
{
    __shared__ float sx[10240];
    __shared__ float sh[10240];
    __shared__ float red[768];
    unsigned* flags = (unsigned*)(ws + WS_E);

    const int bid = blockIdx.x;
    const int tid = threadIdx.x;

    int job, jbase;
    if      (bid < 32)  { job = 0; jbase = bid * 16; }
    else if (bid < 96)  { job = 1; jbase = (bid - 32) * 8; }
    else if (bid < 160) { job = 2; jbase = (bid - 96) * 8; }
    else if (bid < 192) { job = 3; jbase = (bid - 160) * 16; }
    else                { job = 4; jbase = (bid - 192) * 16; }

    const int ks = tid & 31;
    const int qh = (tid >> 5) & 1;
    const int cs = tid >> 6;

    // ---- poll table: [range0 = producers (off 0)], [range1 = anti-deps (off 1)] ----
    int rs0, rc0, rs1, rc1;
    if      (job == 0) { rs0 = 0;   rc0 = 32;  rs1 = 32;  rc1 = 64; }
    else if (job == 1) { rs0 = 0;   rc0 = 96;  rs1 = 96;  rc1 = 64; }
    else if (job == 2) { rs0 = 32;  rc0 = 128; rs1 = 160; rc1 = 32; }
    else if (job == 3) { rs0 = 96;  rc0 = 64;  rs1 = 192; rc1 = 32; }
    else               { rs0 = 160; rc0 = 32;  rs1 = 0;   rc1 = 0;  }

    int fidl[3], offl[3];
    #pragma unroll
    for (int e = 0; e < 3; ++e) {
        int idx = (tid & 63) + e * 64;
        if (idx < rc0)            { fidl[e] = rs0 + idx;         offl[e] = 0; }
        else if (idx < rc0 + rc1) { fidl[e] = rs1 + (idx - rc0); offl[e] = 1; }
        else                      { fidl[e] = bid;               offl[e] = 1; }
    }

    // ---- one-time weight preload into registers ----
    float w[6][16];
    if (job <= 2) {
        const float* Wsrc;
        int colbase;
        if (job == 0) { Wsrc = W_hh; colbase = jbase + cs * 2; }
        else {
            Wsrc = ((cs & 1) ? W_hh : W_ih) + (size_t)job * H * TH3;
            colbase = jbase + (cs >> 1) * 2;
        }
        #pragma unroll
        for (int f = 0; f < 6; ++f) {
            int g = f >> 1, c = f & 1;
            #pragma unroll
            for (int kk = 0; kk < 16; ++kk)
                w[f][kk] = Wsrc[(size_t)(kk * 32 + ks) * TH3 + g * 512 + colbase + c];
        }
    } else {
        const float* base = (job == 3) ? Wa1 : Wa2;
        int colbase = jbase + cs * 2;
        #pragma unroll
        for (int f = 0; f < 2; ++f)
            #pragma unroll
            for (int kk = 0; kk < 16; ++kk)
                w[f][kk] = base[(size_t)(kk * 32 + ks) * H + colbase + f];
    }

    // ---- epilogue constants (biases + running h for own cols) ----
    float c_bi0 = 0, c_bi1 = 0, c_bi2 = 0, c_bh0 = 0, c_bh1 = 0, c_bh2 = 0;
    float hp = 0.f, c_ba = 0.f;
    if (job == 0 && tid < 256) {
        int b = tid & 15, j2 = tid >> 4, jc = jbase + j2;
        c_bi0 = b_ih[jc]; c_bi1 = b_ih[512 + jc]; c_bi2 = b_ih[1024 + jc];
        c_bh0 = b_hh[jc]; c_bh1 = b_hh[512 + jc]; c_bh2 = b_hh[1024 + jc];
        hp = ws[WS_STATE(0, 2) + jc * 16 + b];
    } else if ((job == 1 || job == 2) && tid < 128) {
        int b = tid & 15, j2 = tid >> 4, jc = jbase + j2;
        const float* bi  = b_ih + job * TH3;
        const float* bhh = b_hh + job * TH3;
        c_bi0 = bi[jc]; c_bi1 = bi[512 + jc]; c_bi2 = bi[1024 + jc];
        c_bh0 = bhh[jc]; c_bh1 = bhh[512 + jc]; c_bh2 = bhh[1024 + jc];
        hp = ws[WS_STATE(job, (job + 2) % 3) + jc * 16 + b];
    } else if (job == 3 && tid < 256) {
        c_ba = ba1[jbase + (tid >> 4)];
    } else if (job == 4 && tid < 256) {
        c_ba = ba2[jbase + (tid & 15)];
    }

    const int k0 = tid >> 2;          // staging: first k row
    const int q4 = (tid & 3) * 4;     // staging: float offset within row
    const bool b0 = (ks & 1), b1 = (ks & 2), b3 = (ks & 8), b4 = (ks & 16);

    for (int s = 0; s < 100; ++s) {
        const int rp = (s + 2) % 3, wp = s % 3;
        const int act = (s >= job && s <= 95 + job);

        if (act) {
            // ---- wait on producer (>=s) / anti-dep (>=s-1) flags: wave 0 only ----
            if (s > 0 && tid < 64) {
                for (;;) {
                    unsigned v0, v1, v2;
                    ld_coh_u32x3(&flags[fidl[0]], &flags[fidl[1]], &flags[fidl[2]],
                                 v0, v1, v2);
                    int ok = ((int)v0 + offl[0] >= s) &&
                             ((int)v1 + offl[1] >= s) &&
                             ((int)v2 + offl[2] >= s);
                    if (__all(ok)) break;
                    __builtin_amdgcn_s_sleep(1);
                }
            }
            __syncthreads();

            // ---- stage state(s) into stride-20 LDS (one L3 round trip) ----
            if (job == 1 || job == 2) {
                const float* sA = ws + WS_STATE(job - 1, rp);
                const float* sB = ws + WS_STATE(job, rp);
                float4 a0, a1, a2, a3, h0, h1, h2, h3;
                ld_coh8(sA + 4 * tid, sA + 4 * (tid + 512),
                        sA + 4 * (tid + 1024), sA + 4 * (tid + 1536),
                        sB + 4 * tid, sB + 4 * (tid + 512),
                        sB + 4 * (tid + 1024), sB + 4 * (tid + 1536),
                        a0, a1, a2, a3, h0, h1, h2, h3);
                *(float4*)&sx[(k0      ) * 20 + q4] = a0;
                *(float4*)&sx[(k0 + 128) * 20 + q4] = a1;
                *(float4*)&sx[(k0 + 256) * 20 + q4] = a2;
                *(float4*)&sx[(k0 + 384) * 20 + q4] = a3;
                *(float4*)&sh[(k0      ) * 20 + q4] = h0;
                *(float4*)&sh[(k0 + 128) * 20 + q4] = h1;
                *(float4*)&sh[(k0 + 256) * 20 + q4] = h2;
                *(float4*)&sh[(k0 + 384) * 20 + q4] = h3;
            } else {
                const float* sA = (job == 0) ? (ws + WS_STATE(0, rp))
                                : (job == 3) ? (ws + WS_STATE(2, rp))
                                             : (ws + WS_A1(rp));
                float4 a0, a1, a2, a3;
                ld_coh4(sA + 4 * tid, sA + 4 * (tid + 512),
                        sA + 4 * (tid + 1024), sA + 4 * (tid + 1536),
                        a0, a1, a2, a3);
                *(float4*)&sx[(k0      ) * 20 + q4] = a0;
                *(float4*)&sx[(k0 + 128) * 20 + q4] = a1;
                *(float4*)&sx[(k0 + 256) * 20 + q4] = a2;
                *(float4*)&sx[(k0 + 384) * 20 + q4] = a3;
            }
            __syncthreads();

            // ---- register-weight dot products ----
            const int rowoff = 8 * qh;
            if (job <= 2) {
                const float* arr = (job != 0 && (cs & 1)) ? sh : sx;
                float acc[6][8];
                #pragma unroll
                for (int f = 0; f < 6; ++f)
                    #pragma unroll
                    for (int i = 0; i < 8; ++i) acc[f][i] = 0.f;
                #pragma unroll
                for (int kk = 0; kk < 16; ++kk) {
                    const float* p = arr + (kk * 32 + ks) * 20 + rowoff;
                    float4 v0 = *(const float4*)p;
                    float4 v1 = *(const float4*)(p + 4);
                    #pragma unroll
                    for (int f = 0; f < 6; ++f) {
                        float wv = w[f][kk];
                        acc[f][0] += wv * v0.x; acc[f][1] += wv * v0.y;
                        acc[f][2] += wv * v0.z; acc[f][3] += wv * v0.w;
                        acc[f][4] += wv * v1.x; acc[f][5] += wv * v1.y;
                        acc[f][6] += wv * v1.z; acc[f][7] += wv * v1.w;
                    }
                }
                // ---- reduce-scatter over ks ----
                float a[6];
                #pragma unroll
                for (int f = 0; f < 6; ++f) {
                    float t[4];
                    #pragma unroll
                    for (int j = 0; j < 4; ++j) {
                        float give = b0 ? acc[f][j] : acc[f][j + 4];
                        float recv = dppmov<DPP_XOR1>(give);
                        float keep = b0 ? acc[f][j + 4] : acc[f][j];
                        t[j] = keep + recv;
                    }
                    float u[2];
                    #pragma unroll
                    for (int j = 0; j < 2; ++j) {
                        float give = b1 ? t[j] : t[j + 2];
                        float recv = dppmov<DPP_XOR2>(give);
                        float keep = b1 ? t[j + 2] : t[j];
                        u[j] = keep + recv;
                    }
                    {
                        float give = b3 ? u[0] : u[1];
                        float recv = dppmov<DPP_XOR8>(give);
                        float keep = b3 ? u[1] : u[0];
                        a[f] = keep + recv;
                    }
                }
                #pragma unroll
                for (int f = 0; f < 6; ++f) a[f] += swzf<SWZ_XOR4>(a[f]);
                float r[3];
                #pragma unroll
                for (int i = 0; i < 3; ++i) {
                    float give = b4 ? a[i] : a[i + 3];
                    float recv = swzf<SWZ_XOR16>(give);
                    float keep = b4 ? a[i + 3] : a[i];
                    r[i] = keep + recv;
                }
                if (!(ks & 4)) {
                    int bl = ((ks & 1) << 2) | (ks & 2) | ((ks >> 3) & 1);
                    int bb = qh * 8 + bl;
                    int fb3 = ((ks >> 4) & 1) * 3;
                    #pragma unroll
                    for (int i = 0; i < 3; ++i) {
                        int f = fb3 + i, g = f >> 1, c = f & 1;
                        int idx = (job == 0)
                            ? g * 256 + (cs * 2 + c) * 16 + bb
                            : (cs & 1) * 384 + g * 128 + ((cs >> 1) * 2 + c) * 16 + bb;
                        red[idx] = r[i];
                    }
                }
            } else {
                float acc[2][8];
                #pragma unroll
                for (int f = 0; f < 2; ++f)
                    #pragma unroll
                    for (int i = 0; i < 8; ++i) acc[f][i] = 0.f;
                #pragma unroll
                for (int kk = 0; kk < 16; ++kk) {
                    const float* p = sx + (kk * 32 + ks) * 20 + rowoff;
                    float4 v0 = *(const float4*)p;
                    float4 v1 = *(const float4*)(p + 4);
                    #pragma unroll
                    for (int f = 0; f < 2; ++f) {
                        float wv = w[f][kk];
                        acc[f][0] += wv * v0.x; acc[f][1] += wv * v0.y;
                        acc[f][2] += wv * v0.z; acc[f][3] += wv * v0.w;
                        acc[f][4] += wv * v1.x; acc[f][5] += wv * v1.y;
                        acc[f][6] += wv * v1.z; acc[f][7] += wv * v1.w;
                    }
                }
                float a[2];
                #pragma unroll
                for (int f = 0; f < 2; ++f) {
                    float t[4];
                    #pragma unroll
                    for (int j = 0; j < 4; ++j) {
                        float give = b0 ? acc[f][j] : acc[f][j + 4];
                        float recv = dppmov<DPP_XOR1>(give);
                        float keep = b0 ? acc[f][j + 4] : acc[f][j];
                        t[j] = keep + recv;
                    }
                    float u[2];
                    #pragma unroll
                    for (int j = 0; j < 2; ++j) {
                        float give = b1 ? t[j] : t[j + 2];
                        float recv = dppmov<DPP_XOR2>(give);
                        float keep = b1 ? t[j + 2] : t[j];
                        u[j] = keep + recv;
                    }
                    float give = b3 ? u[0] : u[1];
                    float recv = dppmov<DPP_XOR8>(give);
                    float keep = b3 ? u[1] : u[0];
                    a[f] = keep + recv;
                }
                a[0] += swzf<SWZ_XOR4>(a[0]);
                a[1] += swzf<SWZ_XOR4>(a[1]);
                float give = b4 ? a[0] : a[1];
                float recv = swzf<SWZ_XOR16>(give);
                float keep = b4 ? a[1] : a[0];
                float r0 = keep + recv;
                if (!(ks & 4)) {
                    int bl = ((ks & 1) << 2) | (ks & 2) | ((ks >> 3) & 1);
                    int bb = qh * 8 + bl;
                    int fb = (ks >> 4) & 1;
                    red[(cs * 2 + fb) * 16 + bb] = r0;
                }
            }
            __syncthreads();

            // ---- epilogue (coherent stores for cross-block state) ----
            if (job == 0) {
                if (tid < 256) {
                    int b = tid & 15, j2 = tid >> 4, jc = jbase + j2;
                    float g0 = red[       j2 * 16 + b];
                    float g1 = red[256  + j2 * 16 + b];
                    float g2 = red[512  + j2 * 16 + b];
                    float r  = sigm_(c_bi0 + g0 + c_bh0);
                    float zg = sigm_(c_bi1 + g1 + c_bh1);
                    float n  = tanhf(c_bi2 + r * (g2 + c_bh2));
                    float hn = (1.f - zg) * n + zg * hp;
                    hp = hn;
                    st_coh1(&ws[WS_STATE(0, wp) + jc * 16 + b], hn);
                }
            } else if (job <= 2) {
                if (tid < 128) {
                    int b = tid & 15, j2 = tid >> 4, jc = jbase + j2;
                    float gi0 = red[        j2 * 16 + b], gh0 = red[384 +       j2 * 16 + b];
                    float gi1 = red[128  +  j2 * 16 + b], gh1 = red[384 + 128 + j2 * 16 + b];
                    float gi2 = red[256  +  j2 * 16 + b], gh2 = red[384 + 256 + j2 * 16 + b];
                    float r  = sigm_(gi0 + c_bi0 + gh0 + c_bh0);
                    float zg = sigm_(gi1 + c_bi1 + gh1 + c_bh1);
                    float n  = tanhf(gi2 + c_bi2 + r * (gh2 + c_bh2));
                    float hn = (1.f - zg) * n + zg * hp;
                    hp = hn;
                    st_coh1(&ws[WS_STATE(job, wp) + jc * 16 + b], hn);
                }
            } else if (job == 3) {
                if (tid < 256) {
                    int b = tid & 15, j2 = tid >> 4, jc = jbase + j2;
                    float v = red[j2 * 16 + b] + c_ba;
                    st_coh1(&ws[WS_A1(wp) + jc * 16 + b], fmaxf(v, 0.f));
                }
            } else {
                if (tid < 256) {
                    int j2 = tid & 15, b = tid >> 4, jc = jbase + j2;
                    float v = red[j2 * 16 + b] + c_ba;
                    ws[WS_ATOMS + ((size_t)(s - 4) * 16 + b) * H + jc] = v;
                }
            }
        }

        // ---- post completion flag (monotone, fire-and-forget) ----
        vm_drain();
        __syncthreads();
        if (tid == 0) st_coh_u32(&flags[bid], (unsigned)(s + 1));
    }
}

// ---------------- argmax over logits (first-max-wins) ----------------
extern "C" __global__ __launch_bounds__(256)
void k_argmax(const float* __restrict__ ws, float* __restrict__ out)
{
    const int t = blockIdx.x;                  // 0..95
    const int wv = threadIdx.x >> 6, lane = threadIdx.x & 63;
    for (int b = wv; b < 16; b += 4) {
        const float* row = ws + WS_ATOMS + ((size_t)t * 16 + b) * H;
        float mx = -3.4028235e38f; int mi = 0;
        #pragma unroll
        for (int c = 0; c < 8; ++c) {
            int idx = lane + c * 64;
            float v = row[idx];
            if (v > mx) { mx = v; mi = idx; }
        }
        #pragma unroll
        for (int off = 32; off >= 1; off >>= 1) {
            float omx = __shfl_down(mx, off);
            int   omi = __shfl_down(mi, off);
            if (omx > mx || (omx == mx && omi < mi)) { mx = omx; mi = omi; }
        }
        if (lane == 0) out[b * 96 + t] = (float)mi;
    }
}

// ---------------- e_i / e_j = atoms @ Wb1 halves, tiled (16 rows reuse) -------
extern "C" __global__ __launch_bounds__(256)
void k_eij(const float* __restrict__ Wb1, const float* __restrict__ bb1,
           float* __restrict__ ws)
{
    __shared__ float aT[8192];                 // [k][b16], 32 KB
    const int bid = blockIdx.x;
    const int t = bid >> 4, m = (bid >> 3) & 1, ct = bid & 7;
    const int tid = threadIdx.x;
    const float* atoms = ws + WS_ATOMS;
    for (int f = tid; f < 2048; f += 256) {    // transpose-stage A tile
        int b = f >> 7, kq = f & 127;
        float4 v = ((const float4*)(atoms + ((size_t)(t * 16 + b)) * H))[kq];
        aT[(kq * 4 + 0) * 16 + b] = v.x;
        aT[(kq * 4 + 1) * 16 + b] = v.y;
        aT[(kq * 4 + 2) * 16 + b] = v.z;
        aT[(kq * 4 + 3) * 16 + b] = v.w;
    }
    __syncthreads();
    const int c = tid & 63, rq = tid >> 6;
    const int col = ct * 64 + c;
    const float* Wp = Wb1 + (size_t)m * H * H + col;
    float a0 = 0, a1 = 0, a2 = 0, a3 = 0;
    #pragma unroll 8
    for (int k = 0; k < 512; ++k) {
        float  wv = Wp[(size_t)k * H];
        float4 av = *(const float4*)&aT[k * 16 + rq * 4];
        a0 += av.x * wv; a1 += av.y * wv; a2 += av.z * wv; a3 += av.w * wv;
    }
    float bb = (m == 0) ? bb1[col] : 0.f;
    a0 += bb; a1 += bb; a2 += bb; a3 += bb;
    float* eb = ws + WS_E + (size_t)(m * 16) * 96 * H;
    eb[((size_t)(rq * 4 + 0) * 96 + t) * H + col] = a0;
    eb[((size_t)(rq * 4 + 1) * 96 + t) * H + col] = a1;
    eb[((size_t)(rq * 4 + 2) * 96 + t) * H + col] = a2;
    eb[((size_t)(rq * 4 + 3) * 96 + t) * H + col] = a3;
}

// ---------------- fused edge MLP: relu(e_i + e_j) @ Wb2 + bb2, diag zeroed ----
extern "C" __global__ __launch_bounds__(256)
void k_edge(const float* __restrict__ Wb2, const float* __restrict__ bb2,
            const float* __restrict__ ws, float* __restrict__ out)
{
    __shared__ float ls[32][260];
    const int bid = blockIdx.x;                // b*36 + it*6 + jt
    const int b = bid / 36, r6 = bid % 36, it = r6 / 6, jt = r6 % 6;
    const int tid = threadIdx.x;
    const int ip = tid & 15, jp = tid >> 4;
    float acc0 = 0, acc1 = 0, acc2 = 0, acc3 = 0;

    for (int ph = 0; ph < 2; ++ph) {
        __syncthreads();
        for (int f = tid; f < 2048; f += 256) {
            int r = f >> 6, c4 = f & 63;
            const float* src = (r < 16)
                ? ws + WS_E + ((size_t)b * 96 + it * 16 + r) * H
                : ws + WS_E + ((size_t)(16 + b) * 96 + jt * 16 + (r - 16)) * H;
            float4 v = *(const float4*)(src + ph * 256 + c4 * 4);
            *(float4*)&ls[r][c4 * 4] = v;
        }
        __syncthreads();
        const float* wb = Wb2 + (size_t)ph * 256 * 4;
        #pragma unroll 2
        for (int hh = 0; hh < 256; hh += 4) {
            float4 ei = *(const float4*)&ls[ip][hh];
            float4 ej = *(const float4*)&ls[16 + jp][hh];
            const float* w = wb + (size_t)hh * 4;
            float v;
            v = fmaxf(ei.x + ej.x, 0.f); acc0 += v * w[0];  acc1 += v * w[1];  acc2 += v * w[2];  acc3 += v * w[3];
            v = fmaxf(ei.y + ej.y, 0.f); acc0 += v * w[4];  acc1 += v * w[5];  acc2 += v * w[6];  acc3 += v * w[7];
            v = fmaxf(ei.z + ej.z, 0.f); acc0 += v * w[8];  acc1 += v * w[9];  acc2 += v * w[10]; acc3 += v * w[11];
            v = fmaxf(ei.w + ej.w, 0.f); acc0 += v * w[12]; acc1 += v * w[13]; acc2 += v * w[14]; acc3 += v * w[15];
        }
    }
    const int i = it * 16 + ip, j = jt * 16 + jp;
    float4 o;
    if (i == j) { o.x = 0.f; o.y = 0.f; o.z = 0.f; o.w = 0.f; }
    else { o.x = acc0 + bb2[0]; o.y = acc1 + bb2[1]; o.z = acc2 + bb2[2]; o.w = acc3 + bb2[3]; }
    *(float4*)(out + 1536 + (((size_t)b * 96 + i) * 96 + j) * 4) = o;
}

// ---------------- host ----------------
extern "C" void kernel_launch(void* const* d_in, const int* in_sizes, int n_in,
                              void* d_out, int out_size, void* d_ws, size_t ws_size,
                              hipStream_t stream)
{
    const float* z    = (const float*)d_in[0];
    const float* Wl2h = (const float*)d_in[1];
    const float* bl2h = (const float*)d_in[2];
    const float* W_ih = (const float*)d_in[3];
    const float* W_hh = (const float*)d_in[4];
    const float* b_ih = (const float*)d_in[5];
    const float* b_hh = (const float*)d_in[6];
    const float* Wa1  = (const float*)d_in[7];
    const float* ba1  = (const float*)d_in[8];
    const float* Wa2  = (const float*)d_in[9];
    const float* ba2  = (const float*)d_in[10];
    const float* Wb1  = (const float*)d_in[11];
    const float* bb1  = (const float*)d_in[12];
    const float* Wb2  = (const float*)d_in[13];
    const float* bb2  = (const float*)d_in[14];
    float* out = (float*)d_out;
    float* ws  = (float*)d_ws;

    hipLaunchKernelGGL(k_init, dim3(32), dim3(256), 0, stream, z, Wl2h, bl2h, ws);

    void* args[] = { (void*)&W_ih, (void*)&W_hh, (void*)&b_ih, (void*)&b_hh,
                     (void*)&Wa1, (void*)&ba1, (void*)&Wa2, (void*)&ba2, (void*)&ws };
    hipLaunchCooperativeKernel((void*)k_gru, dim3(GRID), dim3(512), args, 0, stream);

    hipLaunchKernelGGL(k_argmax, dim3(96), dim3(256), 0, stream, ws, out);
    hipLaunchKernelGGL(k_eij, dim3(1536), dim3(256), 0, stream, Wb1, bb1, ws);
    hipLaunchKernelGGL(k_edge, dim3(576), dim3(256), 0, stream, Wb2, bb2, ws, out);
}

// Round 8
// 900.397 us; speedup vs baseline: 1.1540x; 1.1540x over previous
//
#include <hip/hip_runtime.h>
#include <math.h>

#define H    512
#define TH3  1536
#define GRID 224

// ---------------- workspace layout (float offsets), P=3 parities ----------------
#define WS_STATE(l,p) ((size_t)((l)*3+(p)) * 8192)          // 0 .. 73728
#define WS_A1(p)      ((size_t)73728 + (size_t)(p)*8192)    // 73728 .. 98304
#define WS_ATOMS      ((size_t)98304)                        // 98304 .. 884736
#define WS_E          ((size_t)884736)                       // e_i/e_j buffers
// flags u32[256] at WS_E during k_gru; k_eij overwrites the region afterwards.

__device__ __forceinline__ float sigm_(float x) { return 1.0f / (1.0f + expf(-x)); }

// ---- LSB stamping: freshness tag lives in the data mantissa LSB ----
__device__ __forceinline__ float stampf(float x, unsigned b) {
    return __uint_as_float((__float_as_uint(x) & ~1u) | b);
}
__device__ __forceinline__ int lsb4ok(float4 v, unsigned e) {
    return ((__float_as_uint(v.x) & 1u) == e) & ((__float_as_uint(v.y) & 1u) == e) &
           ((__float_as_uint(v.z) & 1u) == e) & ((__float_as_uint(v.w) & 1u) == e);
}

// ---- coherent (L3-point) memory helpers: bypass L1+L2 via sc0 sc1 ----
__device__ __forceinline__ void ld_coh4(const float* p0, const float* p1,
                                        const float* p2, const float* p3,
                                        float4& a, float4& b, float4& c, float4& d)
{
    asm volatile(
        "global_load_dwordx4 %0, %4, off sc0 sc1\n\t"
        "global_load_dwordx4 %1, %5, off sc0 sc1\n\t"
        "global_load_dwordx4 %2, %6, off sc0 sc1\n\t"
        "global_load_dwordx4 %3, %7, off sc0 sc1\n\t"
        "s_waitcnt vmcnt(0)"
        : "=&v"(a), "=&v"(b), "=&v"(c), "=&v"(d)
        : "v"(p0), "v"(p1), "v"(p2), "v"(p3)
        : "memory");
}

__device__ __forceinline__ void ld_coh8(const float* p0, const float* p1,
                                        const float* p2, const float* p3,
                                        const float* p4, const float* p5,
                                        const float* p6, const float* p7,
                                        float4& a, float4& b, float4& c, float4& d,
                                        float4& e, float4& f, float4& g, float4& h)
{
    asm volatile(
        "global_load_dwordx4 %0, %8, off sc0 sc1\n\t"
        "global_load_dwordx4 %1, %9, off sc0 sc1\n\t"
        "global_load_dwordx4 %2, %10, off sc0 sc1\n\t"
        "global_load_dwordx4 %3, %11, off sc0 sc1\n\t"
        "global_load_dwordx4 %4, %12, off sc0 sc1\n\t"
        "global_load_dwordx4 %5, %13, off sc0 sc1\n\t"
        "global_load_dwordx4 %6, %14, off sc0 sc1\n\t"
        "global_load_dwordx4 %7, %15, off sc0 sc1\n\t"
        "s_waitcnt vmcnt(0)"
        : "=&v"(a), "=&v"(b), "=&v"(c), "=&v"(d),
          "=&v"(e), "=&v"(f), "=&v"(g), "=&v"(h)
        : "v"(p0), "v"(p1), "v"(p2), "v"(p3),
          "v"(p4), "v"(p5), "v"(p6), "v"(p7)
        : "memory");
}

__device__ __forceinline__ void st_coh1(float* p, float v) {
    asm volatile("global_store_dword %0, %1, off sc0 sc1" :: "v"(p), "v"(v) : "memory");
}

__device__ __forceinline__ void ld_coh_u32x2(const unsigned* p0, const unsigned* p1,
                                             unsigned& a, unsigned& b)
{
    asm volatile(
        "global_load_dword %0, %2, off sc0 sc1\n\t"
        "global_load_dword %1, %3, off sc0 sc1\n\t"
        "s_waitcnt vmcnt(0)"
        : "=&v"(a), "=&v"(b)
        : "v"(p0), "v"(p1)
        : "memory");
}

__device__ __forceinline__ void st_coh_u32(unsigned* p, unsigned v) {
    asm volatile("global_store_dword %0, %1, off sc0 sc1" :: "v"(p), "v"(v) : "memory");
}

__device__ __forceinline__ void vm_drain() {
    asm volatile("s_waitcnt vmcnt(0)" ::: "memory");
}

// ---- cross-lane helpers: DPP (VALU) for xor1/xor2/xor8, ds_swizzle for xor4/xor16 ----
template<int CTRL>
__device__ __forceinline__ float dppmov(float v) {
    return __int_as_float(__builtin_amdgcn_update_dpp(
        0, __float_as_int(v), CTRL, 0xF, 0xF, true));
}
#define DPP_XOR1 0xB1   // quad_perm(1,0,3,2)
#define DPP_XOR2 0x4E   // quad_perm(2,3,0,1)
#define DPP_XOR8 0x128  // row_ror:8  (== xor8 within 16)

template<int PAT>
__device__ __forceinline__ float swzf(float v) {
    return __int_as_float(__builtin_amdgcn_ds_swizzle(__float_as_int(v), PAT));
}
#define SWZ_XOR4  0x101F
#define SWZ_XOR16 0x401F

// ---------------- h_init: z @ W_l2h + b_l2h, LSB-stamped parities ----------------
// real data -> parity (l+2)%3 with LSB of slot -1..1; other parities get inverted-
// LSB placeholders so stale/poison can never pass the freshness check.
extern "C" __global__ __launch_bounds__(256)
void k_init(const float* __restrict__ z, const float* __restrict__ Wl2h,
            const float* __restrict__ bl2h, float* __restrict__ ws)
{
    if (blockIdx.x == 0)
        ((unsigned*)(ws + WS_E))[threadIdx.x] = 0u;   // flags[0..255]
    const int t  = threadIdx.x;
    const int jl = t & 15, b = t >> 4;
    const int j  = blockIdx.x * 16 + jl;
    float acc = 0.f;
    #pragma unroll 4
    for (int k = 0; k < H; ++k)
        acc += z[b * H + k] * Wl2h[(size_t)k * H + j];
    acc += bl2h[j];

    // stamp tables (see analysis): real LSB per layer; placeholder LSB per (l,p)
    const unsigned realLsb[3] = { 1u, 0u, 1u };
    const int preh[3][3] = { { 1, 0, -1 },     // h0: p0=1, p1=0, p2=real
                             { -1, 0, 1 },     // h1: p0=real, p1=0, p2=1
                             { 0, -1, 1 } };   // h2: p0=0, p1=real, p2=1
    const unsigned preA1[3] = { 0u, 1u, 0u };
    #pragma unroll
    for (int l = 0; l < 3; ++l)
        #pragma unroll
        for (int p = 0; p < 3; ++p) {
            float v = (preh[l][p] < 0) ? stampf(acc, realLsb[l])
                                       : __uint_as_float((unsigned)preh[l][p]);
            ws[WS_STATE(l, p) + j * 16 + b] = v;
        }
    #pragma unroll
    for (int p = 0; p < 3; ++p)
        ws[WS_A1(p) + j * 16 + b] = __uint_as_float(preA1[p]);
}

// ---------------- persistent pipelined GRU + MLP decoder ----------------
// blocks: [0,32)=L0 (16 cols), [32,96)=L1 (8 cols), [96,160)=L2 (8),
//         [160,192)=A1 (16), [192,224)=LG (16).  512 threads.
// Forward deps: LSB-in-data freshness check fused into the staging load (1 RT).
// Anti-deps: consumer-completion flags with 1-slot slack, polled by wave 0 only,
// concurrently with staging (joined at the pre-compute barrier).
__global__ __launch_bounds__(512, 2)
void k_gru(const float* __restrict__ W_ih, const float* __restrict__ W_hh,
           const float* __restrict__ b_ih, const float* __restrict__ b_hh,
           const float* __restrict__ Wa1,  const float* __restrict__ ba1,
           const float* __restrict__ Wa2,  const float* __restrict__ ba2,
           float* __restrict__ ws)
{
    __shared__ float sx[10240];
    __shared__ float sh[10240];
    __shared__ float red[768];
    unsigned* flags = (unsigned*)(ws + WS_E);

    const int bid = blockIdx.x;
    const int tid = threadIdx.x;

    int job, jbase;
    if      (bid < 32)  { job = 0; jbase = bid * 16; }
    else if (bid < 96)  { job = 1; jbase = (bid - 32) * 8; }
    else if (bid < 160) { job = 2; jbase = (bid - 96) * 8; }
    else if (bid < 192) { job = 3; jbase = (bid - 160) * 16; }
    else                { job = 4; jbase = (bid - 192) * 16; }

    const int ks = tid & 31;
    const int qh = (tid >> 5) & 1;
    const int cs = tid >> 6;

    // ---- anti-dep poll set: consumers of the buffer this stage writes ----
    int rs0, rc0;
    if      (job == 0) { rs0 = 0;   rc0 = 96;  }
    else if (job == 1) { rs0 = 32;  rc0 = 128; }
    else if (job == 2) { rs0 = 96;  rc0 = 96;  }
    else if (job == 3) { rs0 = 192; rc0 = 32;  }
    else               { rs0 = 0;   rc0 = 0;   }
    int fidl[2];
    #pragma unroll
    for (int e = 0; e < 2; ++e) {
        int idx = (tid & 63) + e * 64;
        fidl[e] = (idx < rc0) ? rs0 + idx : bid;   // own flag trivially passes
    }

    // ---- one-time weight preload into registers ----
    float w[6][16];
    if (job <= 2) {
        const float* Wsrc;
        int colbase;
        if (job == 0) { Wsrc = W_hh; colbase = jbase + cs * 2; }
        else {
            Wsrc = ((cs & 1) ? W_hh : W_ih) + (size_t)job * H * TH3;
            colbase = jbase + (cs >> 1) * 2;
        }
        #pragma unroll
        for (int f = 0; f < 6; ++f) {
            int g = f >> 1, c = f & 1;
            #pragma unroll
            for (int kk = 0; kk < 16; ++kk)
                w[f][kk] = Wsrc[(size_t)(kk * 32 + ks) * TH3 + g * 512 + colbase + c];
        }
    } else {
        const float* base = (job == 3) ? Wa1 : Wa2;
        int colbase = jbase + cs * 2;
        #pragma unroll
        for (int f = 0; f < 2; ++f)
            #pragma unroll
            for (int kk = 0; kk < 16; ++kk)
                w[f][kk] = base[(size_t)(kk * 32 + ks) * H + colbase + f];
    }

    // ---- epilogue constants (biases + running h for own cols) ----
    float c_bi0 = 0, c_bi1 = 0, c_bi2 = 0, c_bh0 = 0, c_bh1 = 0, c_bh2 = 0;
    float hp = 0.f, c_ba = 0.f;
    if (job == 0 && tid < 256) {
        int b = tid & 15, j2 = tid >> 4, jc = jbase + j2;
        c_bi0 = b_ih[jc]; c_bi1 = b_ih[512 + jc]; c_bi2 = b_ih[1024 + jc];
        c_bh0 = b_hh[jc]; c_bh1 = b_hh[512 + jc]; c_bh2 = b_hh[1024 + jc];
        hp = ws[WS_STATE(0, 2) + jc * 16 + b];
    } else if ((job == 1 || job == 2) && tid < 128) {
        int b = tid & 15, j2 = tid >> 4, jc = jbase + j2;
        const float* bi  = b_ih + job * TH3;
        const float* bhh = b_hh + job * TH3;
        c_bi0 = bi[jc]; c_bi1 = bi[512 + jc]; c_bi2 = bi[1024 + jc];
        c_bh0 = bhh[jc]; c_bh1 = bhh[512 + jc]; c_bh2 = bhh[1024 + jc];
        hp = ws[WS_STATE(job, (job + 2) % 3) + jc * 16 + b];
    } else if (job == 3 && tid < 256) {
        c_ba = ba1[jbase + (tid >> 4)];
    } else if (job == 4 && tid < 256) {
        c_ba = ba2[jbase + (tid & 15)];
    }

    const int k0 = tid >> 2;          // staging: first k row
    const int q4 = (tid & 3) * 4;     // staging: float offset within row
    const bool b0 = (ks & 1), b1 = (ks & 2), b3 = (ks & 8), b4 = (ks & 16);

    for (int s = 0; s < 100; ++s) {
        const int rp = (s + 2) % 3, wp = s % 3;
        const int act = (s >= job && s <= 95 + job);

        if (act) {
            const unsigned expb = (unsigned)((s + 1) & 1);   // == (s-1)&1

            // ---- anti-dep poll (wave 0, concurrent with other waves' staging) ----
            if (tid < 64 && s >= 2) {
                unsigned lim = (unsigned)(s - 1);
                for (;;) {
                    unsigned v0, v1;
                    ld_coh_u32x2(&flags[fidl[0]], &flags[fidl[1]], v0, v1);
                    int ok = (v0 >= lim) && (v1 >= lim);
                    if (__all(ok)) break;
                    __builtin_amdgcn_s_sleep(1);
                }
            }

            // ---- fused detect+stage: speculative coherent load + LSB check ----
            if (job == 1 || job == 2) {
                const float* sA = ws + WS_STATE(job - 1, rp);
                const float* sB = ws + WS_STATE(job, rp);
                float4 xa, xb, xc, xd, ha, hb, hc, hd;
                for (;;) {
                    ld_coh8(sA + 4 * tid, sA + 4 * (tid + 512),
                            sA + 4 * (tid + 1024), sA + 4 * (tid + 1536),
                            sB + 4 * tid, sB + 4 * (tid + 512),
                            sB + 4 * (tid + 1024), sB + 4 * (tid + 1536),
                            xa, xb, xc, xd, ha, hb, hc, hd);
                    int ok = lsb4ok(xa, expb) & lsb4ok(xb, expb) &
                             lsb4ok(xc, expb) & lsb4ok(xd, expb) &
                             lsb4ok(ha, expb) & lsb4ok(hb, expb) &
                             lsb4ok(hc, expb) & lsb4ok(hd, expb);
                    if (__all(ok)) break;
                    __builtin_amdgcn_s_sleep(1);
                }
                *(float4*)&sx[(k0      ) * 20 + q4] = xa;
                *(float4*)&sx[(k0 + 128) * 20 + q4] = xb;
                *(float4*)&sx[(k0 + 256) * 20 + q4] = xc;
                *(float4*)&sx[(k0 + 384) * 20 + q4] = xd;
                *(float4*)&sh[(k0      ) * 20 + q4] = ha;
                *(float4*)&sh[(k0 + 128) * 20 + q4] = hb;
                *(float4*)&sh[(k0 + 256) * 20 + q4] = hc;
                *(float4*)&sh[(k0 + 384) * 20 + q4] = hd;
            } else {
                const float* sA = (job == 0) ? (ws + WS_STATE(0, rp))
                                : (job == 3) ? (ws + WS_STATE(2, rp))
                                             : (ws + WS_A1(rp));
                float4 xa, xb, xc, xd;
                for (;;) {
                    ld_coh4(sA + 4 * tid, sA + 4 * (tid + 512),
                            sA + 4 * (tid + 1024), sA + 4 * (tid + 1536),
                            xa, xb, xc, xd);
                    int ok = lsb4ok(xa, expb) & lsb4ok(xb, expb) &
                             lsb4ok(xc, expb) & lsb4ok(xd, expb);
                    if (__all(ok)) break;
                    __builtin_amdgcn_s_sleep(1);
                }
                *(float4*)&sx[(k0      ) * 20 + q4] = xa;
                *(float4*)&sx[(k0 + 128) * 20 + q4] = xb;
                *(float4*)&sx[(k0 + 256) * 20 + q4] = xc;
                *(float4*)&sx[(k0 + 384) * 20 + q4] = xd;
            }
            __syncthreads();

            // ---- register-weight dot products ----
            const int rowoff = 8 * qh;
            if (job <= 2) {
                const float* arr = (job != 0 && (cs & 1)) ? sh : sx;
                float acc[6][8];
                #pragma unroll
                for (int f = 0; f < 6; ++f)
                    #pragma unroll
                    for (int i = 0; i < 8; ++i) acc[f][i] = 0.f;
                #pragma unroll
                for (int kk = 0; kk < 16; ++kk) {
                    const float* p = arr + (kk * 32 + ks) * 20 + rowoff;
                    float4 v0 = *(const float4*)p;
                    float4 v1 = *(const float4*)(p + 4);
                    #pragma unroll
                    for (int f = 0; f < 6; ++f) {
                        float wv = w[f][kk];
                        acc[f][0] += wv * v0.x; acc[f][1] += wv * v0.y;
                        acc[f][2] += wv * v0.z; acc[f][3] += wv * v0.w;
                        acc[f][4] += wv * v1.x; acc[f][5] += wv * v1.y;
                        acc[f][6] += wv * v1.z; acc[f][7] += wv * v1.w;
                    }
                }
                // ---- reduce-scatter over ks ----
                float a[6];
                #pragma unroll
                for (int f = 0; f < 6; ++f) {
                    float t[4];
                    #pragma unroll
                    for (int j = 0; j < 4; ++j) {
                        float give = b0 ? acc[f][j] : acc[f][j + 4];
                        float recv = dppmov<DPP_XOR1>(give);
                        float keep = b0 ? acc[f][j + 4] : acc[f][j];
                        t[j] = keep + recv;
                    }
                    float u[2];
                    #pragma unroll
                    for (int j = 0; j < 2; ++j) {
                        float give = b1 ? t[j] : t[j + 2];
                        float recv = dppmov<DPP_XOR2>(give);
                        float keep = b1 ? t[j + 2] : t[j];
                        u[j] = keep + recv;
                    }
                    {
                        float give = b3 ? u[0] : u[1];
                        float recv = dppmov<DPP_XOR8>(give);
                        float keep = b3 ? u[1] : u[0];
                        a[f] = keep + recv;
                    }
                }
                #pragma unroll
                for (int f = 0; f < 6; ++f) a[f] += swzf<SWZ_XOR4>(a[f]);
                float r[3];
                #pragma unroll
                for (int i = 0; i < 3; ++i) {
                    float give = b4 ? a[i] : a[i + 3];
                    float recv = swzf<SWZ_XOR16>(give);
                    float keep = b4 ? a[i + 3] : a[i];
                    r[i] = keep + recv;
                }
                if (!(ks & 4)) {
                    int bl = ((ks & 1) << 2) | (ks & 2) | ((ks >> 3) & 1);
                    int bb = qh * 8 + bl;
                    int fb3 = ((ks >> 4) & 1) * 3;
                    #pragma unroll
                    for (int i = 0; i < 3; ++i) {
                        int f = fb3 + i, g = f >> 1, c = f & 1;
                        int idx = (job == 0)
                            ? g * 256 + (cs * 2 + c) * 16 + bb
                            : (cs & 1) * 384 + g * 128 + ((cs >> 1) * 2 + c) * 16 + bb;
                        red[idx] = r[i];
                    }
                }
            } else {
                float acc[2][8];
                #pragma unroll
                for (int f = 0; f < 2; ++f)
                    #pragma unroll
                    for (int i = 0; i < 8; ++i) acc[f][i] = 0.f;
                #pragma unroll
                for (int kk = 0; kk < 16; ++kk) {
                    const float* p = sx + (kk * 32 + ks) * 20 + rowoff;
                    float4 v0 = *(const float4*)p;
                    float4 v1 = *(const float4*)(p + 4);
                    #pragma unroll
                    for (int f = 0; f < 2; ++f) {
                        float wv = w[f][kk];
                        acc[f][0] += wv * v0.x; acc[f][1] += wv * v0.y;
                        acc[f][2] += wv * v0.z; acc[f][3] += wv * v0.w;
                        acc[f][4] += wv * v1.x; acc[f][5] += wv * v1.y;
                        acc[f][6] += wv * v1.z; acc[f][7] += wv * v1.w;
                    }
                }
                float a[2];
                #pragma unroll
                for (int f = 0; f < 2; ++f) {
                    float t[4];
                    #pragma unroll
                    for (int j = 0; j < 4; ++j) {
                        float give = b0 ? acc[f][j] : acc[f][j + 4];
                        float recv = dppmov<DPP_XOR1>(give);
                        float keep = b0 ? acc[f][j + 4] : acc[f][j];
                        t[j] = keep + recv;
                    }
                    float u[2];
                    #pragma unroll
                    for (int j = 0; j < 2; ++j) {
                        float give = b1 ? t[j] : t[j + 2];
                        float recv = dppmov<DPP_XOR2>(give);
                        float keep = b1 ? t[j + 2] : t[j];
                        u[j] = keep + recv;
                    }
                    float give = b3 ? u[0] : u[1];
                    float recv = dppmov<DPP_XOR8>(give);
                    float keep = b3 ? u[1] : u[0];
                    a[f] = keep + recv;
                }
                a[0] += swzf<SWZ_XOR4>(a[0]);
                a[1] += swzf<SWZ_XOR4>(a[1]);
                float give = b4 ? a[0] : a[1];
                float recv = swzf<SWZ_XOR16>(give);
                float keep = b4 ? a[1] : a[0];
                float r0 = keep + recv;
                if (!(ks & 4)) {
                    int bl = ((ks & 1) << 2) | (ks & 2) | ((ks >> 3) & 1);
                    int bb = qh * 8 + bl;
                    int fb = (ks >> 4) & 1;
                    red[(cs * 2 + fb) * 16 + bb] = r0;
                }
            }
            __syncthreads();

            // ---- epilogue (LSB-stamped coherent stores for cross-block state) ----
            const unsigned myb = (unsigned)(s & 1);
            if (job == 0) {
                if (tid < 256) {
                    int b = tid & 15, j2 = tid >> 4, jc = jbase + j2;
                    float g0 = red[       j2 * 16 + b];
                    float g1 = red[256  + j2 * 16 + b];
                    float g2 = red[512  + j2 * 16 + b];
                    float r  = sigm_(c_bi0 + g0 + c_bh0);
                    float zg = sigm_(c_bi1 + g1 + c_bh1);
                    float n  = tanhf(c_bi2 + r * (g2 + c_bh2));
                    float hn = (1.f - zg) * n + zg * hp;
                    hp = hn;
                    st_coh1(&ws[WS_STATE(0, wp) + jc * 16 + b], stampf(hn, myb));
                }
            } else if (job <= 2) {
                if (tid < 128) {
                    int b = tid & 15, j2 = tid >> 4, jc = jbase + j2;
                    float gi0 = red[        j2 * 16 + b], gh0 = red[384 +       j2 * 16 + b];
                    float gi1 = red[128  +  j2 * 16 + b], gh1 = red[384 + 128 + j2 * 16 + b];
                    float gi2 = red[256  +  j2 * 16 + b], gh2 = red[384 + 256 + j2 * 16 + b];
                    float r  = sigm_(gi0 + c_bi0 + gh0 + c_bh0);
                    float zg = sigm_(gi1 + c_bi1 + gh1 + c_bh1);
                    float n  = tanhf(gi2 + c_bi2 + r * (gh2 + c_bh2));
                    float hn = (1.f - zg) * n + zg * hp;
                    hp = hn;
                    st_coh1(&ws[WS_STATE(job, wp) + jc * 16 + b], stampf(hn, myb));
                }
            } else if (job == 3) {
                if (tid < 256) {
                    int b = tid & 15, j2 = tid >> 4, jc = jbase + j2;
                    float v = red[j2 * 16 + b] + c_ba;
                    st_coh1(&ws[WS_A1(wp) + jc * 16 + b], stampf(fmaxf(v, 0.f), myb));
                }
            } else {
                if (tid < 256) {
                    int j2 = tid & 15, b = tid >> 4, jc = jbase + j2;
                    float v = red[j2 * 16 + b] + c_ba;
                    ws[WS_ATOMS + ((size_t)(s - 4) * 16 + b) * H + jc] = v;
                }
            }
        }

        // ---- post completion flag (anti-dep bookkeeping, off critical path) ----
        vm_drain();
        __syncthreads();
        if (tid == 0) st_coh_u32(&flags[bid], (unsigned)(s + 1));
    }
}

// ---------------- argmax over logits (first-max-wins) ----------------
extern "C" __global__ __launch_bounds__(256)
void k_argmax(const float* __restrict__ ws, float* __restrict__ out)
{
    const int t = blockIdx.x;                  // 0..95
    const int wv = threadIdx.x >> 6, lane = threadIdx.x & 63;
    for (int b = wv; b < 16; b += 4) {
        const float* row = ws + WS_ATOMS + ((size_t)t * 16 + b) * H;
        float mx = -3.4028235e38f; int mi = 0;
        #pragma unroll
        for (int c = 0; c < 8; ++c) {
            int idx = lane + c * 64;
            float v = row[idx];
            if (v > mx) { mx = v; mi = idx; }
        }
        #pragma unroll
        for (int off = 32; off >= 1; off >>= 1) {
            float omx = __shfl_down(mx, off);
            int   omi = __shfl_down(mi, off);
            if (omx > mx || (omx == mx && omi < mi)) { mx = omx; mi = omi; }
        }
        if (lane == 0) out[b * 96 + t] = (float)mi;
    }
}

// ---------------- e_i / e_j = atoms @ Wb1 halves, tiled (16 rows reuse) -------
extern "C" __global__ __launch_bounds__(256)
void k_eij(const float* __restrict__ Wb1, const float* __restrict__ bb1,
           float* __restrict__ ws)
{
    __shared__ float aT[8192];                 // [k][b16], 32 KB
    const int bid = blockIdx.x;
    const int t = bid >> 4, m = (bid >> 3) & 1, ct = bid & 7;
    const int tid = threadIdx.x;
    const float* atoms = ws + WS_ATOMS;
    for (int f = tid; f < 2048; f += 256) {    // transpose-stage A tile
        int b = f >> 7, kq = f & 127;
        float4 v = ((const float4*)(atoms + ((size_t)(t * 16 + b)) * H))[kq];
        aT[(kq * 4 + 0) * 16 + b] = v.x;
        aT[(kq * 4 + 1) * 16 + b] = v.y;
        aT[(kq * 4 + 2) * 16 + b] = v.z;
        aT[(kq * 4 + 3) * 16 + b] = v.w;
    }
    __syncthreads();
    const int c = tid & 63, rq = tid >> 6;
    const int col = ct * 64 + c;
    const float* Wp = Wb1 + (size_t)m * H * H + col;
    float a0 = 0, a1 = 0, a2 = 0, a3 = 0;
    #pragma unroll 8
    for (int k = 0; k < 512; ++k) {
        float  wv = Wp[(size_t)k * H];
        float4 av = *(const float4*)&aT[k * 16 + rq * 4];
        a0 += av.x * wv; a1 += av.y * wv; a2 += av.z * wv; a3 += av.w * wv;
    }
    float bb = (m == 0) ? bb1[col] : 0.f;
    a0 += bb; a1 += bb; a2 += bb; a3 += bb;
    float* eb = ws + WS_E + (size_t)(m * 16) * 96 * H;
    eb[((size_t)(rq * 4 + 0) * 96 + t) * H + col] = a0;
    eb[((size_t)(rq * 4 + 1) * 96 + t) * H + col] = a1;
    eb[((size_t)(rq * 4 + 2) * 96 + t) * H + col] = a2;
    eb[((size_t)(rq * 4 + 3) * 96 + t) * H + col] = a3;
}

// ---------------- fused edge MLP: relu(e_i + e_j) @ Wb2 + bb2, diag zeroed ----
extern "C" __global__ __launch_bounds__(256)
void k_edge(const float* __restrict__ Wb2, const float* __restrict__ bb2,
            const float* __restrict__ ws, float* __restrict__ out)
{
    __shared__ float ls[32][260];
    const int bid = blockIdx.x;                // b*36 + it*6 + jt
    const int b = bid / 36, r6 = bid % 36, it = r6 / 6, jt = r6 % 6;
    const int tid = threadIdx.x;
    const int ip = tid & 15, jp = tid >> 4;
    float acc0 = 0, acc1 = 0, acc2 = 0, acc3 = 0;

    for (int ph = 0; ph < 2; ++ph) {
        __syncthreads();
        for (int f = tid; f < 2048; f += 256) {
            int r = f >> 6, c4 = f & 63;
            const float* src = (r < 16)
                ? ws + WS_E + ((size_t)b * 96 + it * 16 + r) * H
                : ws + WS_E + ((size_t)(16 + b) * 96 + jt * 16 + (r - 16)) * H;
            float4 v = *(const float4*)(src + ph * 256 + c4 * 4);
            *(float4*)&ls[r][c4 * 4] = v;
        }
        __syncthreads();
        const float* wb = Wb2 + (size_t)ph * 256 * 4;
        #pragma unroll 2
        for (int hh = 0; hh < 256; hh += 4) {
            float4 ei = *(const float4*)&ls[ip][hh];
            float4 ej = *(const float4*)&ls[16 + jp][hh];
            const float* w = wb + (size_t)hh * 4;
            float v;
            v = fmaxf(ei.x + ej.x, 0.f); acc0 += v * w[0];  acc1 += v * w[1];  acc2 += v * w[2];  acc3 += v * w[3];
            v = fmaxf(ei.y + ej.y, 0.f); acc0 += v * w[4];  acc1 += v * w[5];  acc2 += v * w[6];  acc3 += v * w[7];
            v = fmaxf(ei.z + ej.z, 0.f); acc0 += v * w[8];  acc1 += v * w[9];  acc2 += v * w[10]; acc3 += v * w[11];
            v = fmaxf(ei.w + ej.w, 0.f); acc0 += v * w[12]; acc1 += v * w[13]; acc2 += v * w[14]; acc3 += v * w[15];
        }
    }
    const int i = it * 16 + ip, j = jt * 16 + jp;
    float4 o;
    if (i == j) { o.x = 0.f; o.y = 0.f; o.z = 0.f; o.w = 0.f; }
    else { o.x = acc0 + bb2[0]; o.y = acc1 + bb2[1]; o.z = acc2 + bb2[2]; o.w = acc3 + bb2[3]; }
    *(float4*)(out + 1536 + (((size_t)b * 96 + i) * 96 + j) * 4) = o;
}

// ---------------- host ----------------
extern "C" void kernel_launch(void* const* d_in, const int* in_sizes, int n_in,
                              void* d_out, int out_size, void* d_ws, size_t ws_size,
                              hipStream_t stream)
{
    const float* z    = (const float*)d_in[0];
    const float* Wl2h = (const float*)d_in[1];
    const float* bl2h = (const float*)d_in[2];
    const float* W_ih = (const float*)d_in[3];
    const float* W_hh = (const float*)d_in[4];
    const float* b_ih = (const float*)d_in[5];
    const float* b_hh = (const float*)d_in[6];
    const float* Wa1  = (const float*)d_in[7];
    const float* ba1  = (const float*)d_in[8];
    const float* Wa2  = (const float*)d_in[9];
    const float* ba2  = (const float*)d_in[10];
    const float* Wb1  = (const float*)d_in[11];
    const float* bb1  = (const float*)d_in[12];
    const float* Wb2  = (const float*)d_in[13];
    const float* bb2  = (const float*)d_in[14];
    float* out = (float*)d_out;
    float* ws  = (float*)d_ws;

    hipLaunchKernelGGL(k_init, dim3(32), dim3(256), 0, stream, z, Wl2h, bl2h, ws);

    void* args[] = { (void*)&W_ih, (void*)&W_hh, (void*)&b_ih, (void*)&b_hh,
                     (void*)&Wa1, (void*)&ba1, (void*)&Wa2, (void*)&ba2, (void*)&ws };
    hipLaunchCooperativeKernel((void*)k_gru, dim3(GRID), dim3(512), args, 0, stream);

    hipLaunchKernelGGL(k_argmax, dim3(96), dim3(256), 0, stream, ws, out);
    hipLaunchKernelGGL(k_eij, dim3(1536), dim3(256), 0, stream, Wb1, bb1, ws);
    hipLaunchKernelGGL(k_edge, dim3(576), dim3(256), 0, stream, Wb2, bb2, ws, out);
}

// Round 9
// 839.803 us; speedup vs baseline: 1.2372x; 1.0722x over previous
//
#include <hip/hip_runtime.h>
#include <math.h>

#define H    512
#define TH3  1536
#define GRID 224

// ---------------- workspace layout (float offsets), P=3 parities ----------------
#define WS_STATE(l,p) ((size_t)((l)*3+(p)) * 8192)          // 0 .. 73728
#define WS_A1(p)      ((size_t)73728 + (size_t)(p)*8192)    // 73728 .. 98304
#define WS_ATOMS      ((size_t)98304)                        // 98304 .. 884736
#define WS_E          ((size_t)884736)                       // e_i/e_j buffers
// flags u32[256] at WS_E during k_gru; k_eij overwrites the region afterwards.

__device__ __forceinline__ float sigm_(float x) { return 1.0f / (1.0f + expf(-x)); }

// ---- LSB stamping: freshness tag lives in the data mantissa LSB ----
__device__ __forceinline__ float stampf(float x, unsigned b) {
    return __uint_as_float((__float_as_uint(x) & ~1u) | b);
}
__device__ __forceinline__ int lsb4ok(float4 v, unsigned e) {
    return ((__float_as_uint(v.x) & 1u) == e) & ((__float_as_uint(v.y) & 1u) == e) &
           ((__float_as_uint(v.z) & 1u) == e) & ((__float_as_uint(v.w) & 1u) == e);
}

// ---- coherent (L3-point) memory helpers: bypass L1+L2 via sc0 sc1 ----
__device__ __forceinline__ void ld_coh4(const float* p0, const float* p1,
                                        const float* p2, const float* p3,
                                        float4& a, float4& b, float4& c, float4& d)
{
    asm volatile(
        "global_load_dwordx4 %0, %4, off sc0 sc1\n\t"
        "global_load_dwordx4 %1, %5, off sc0 sc1\n\t"
        "global_load_dwordx4 %2, %6, off sc0 sc1\n\t"
        "global_load_dwordx4 %3, %7, off sc0 sc1\n\t"
        "s_waitcnt vmcnt(0)"
        : "=&v"(a), "=&v"(b), "=&v"(c), "=&v"(d)
        : "v"(p0), "v"(p1), "v"(p2), "v"(p3)
        : "memory");
}

__device__ __forceinline__ void ld_coh8(const float* p0, const float* p1,
                                        const float* p2, const float* p3,
                                        const float* p4, const float* p5,
                                        const float* p6, const float* p7,
                                        float4& a, float4& b, float4& c, float4& d,
                                        float4& e, float4& f, float4& g, float4& h)
{
    asm volatile(
        "global_load_dwordx4 %0, %8, off sc0 sc1\n\t"
        "global_load_dwordx4 %1, %9, off sc0 sc1\n\t"
        "global_load_dwordx4 %2, %10, off sc0 sc1\n\t"
        "global_load_dwordx4 %3, %11, off sc0 sc1\n\t"
        "global_load_dwordx4 %4, %12, off sc0 sc1\n\t"
        "global_load_dwordx4 %5, %13, off sc0 sc1\n\t"
        "global_load_dwordx4 %6, %14, off sc0 sc1\n\t"
        "global_load_dwordx4 %7, %15, off sc0 sc1\n\t"
        "s_waitcnt vmcnt(0)"
        : "=&v"(a), "=&v"(b), "=&v"(c), "=&v"(d),
          "=&v"(e), "=&v"(f), "=&v"(g), "=&v"(h)
        : "v"(p0), "v"(p1), "v"(p2), "v"(p3),
          "v"(p4), "v"(p5), "v"(p6), "v"(p7)
        : "memory");
}

__device__ __forceinline__ void st_coh1(float* p, float v) {
    asm volatile("global_store_dword %0, %1, off sc0 sc1" :: "v"(p), "v"(v) : "memory");
}

__device__ __forceinline__ void ld_coh_u32x2(const unsigned* p0, const unsigned* p1,
                                             unsigned& a, unsigned& b)
{
    asm volatile(
        "global_load_dword %0, %2, off sc0 sc1\n\t"
        "global_load_dword %1, %3, off sc0 sc1\n\t"
        "s_waitcnt vmcnt(0)"
        : "=&v"(a), "=&v"(b)
        : "v"(p0), "v"(p1)
        : "memory");
}

__device__ __forceinline__ void st_coh_u32(unsigned* p, unsigned v) {
    asm volatile("global_store_dword %0, %1, off sc0 sc1" :: "v"(p), "v"(v) : "memory");
}

__device__ __forceinline__ void vm_drain() {
    asm volatile("s_waitcnt vmcnt(0)" ::: "memory");
}

// ---- cross-lane helpers: DPP (VALU) for xor1/xor2/xor8, ds_swizzle for xor4/xor16 ----
template<int CTRL>
__device__ __forceinline__ float dppmov(float v) {
    return __int_as_float(__builtin_amdgcn_update_dpp(
        0, __float_as_int(v), CTRL, 0xF, 0xF, true));
}
#define DPP_XOR1 0xB1   // quad_perm(1,0,3,2)
#define DPP_XOR2 0x4E   // quad_perm(2,3,0,1)
#define DPP_XOR8 0x128  // row_ror:8  (== xor8 within 16)

template<int PAT>
__device__ __forceinline__ float swzf(float v) {
    return __int_as_float(__builtin_amdgcn_ds_swizzle(__float_as_int(v), PAT));
}
#define SWZ_XOR4  0x101F
#define SWZ_XOR16 0x401F

// ---------------- h_init: z @ W_l2h + b_l2h, LSB-stamped parities ----------------
extern "C" __global__ __launch_bounds__(256)
void k_init(const float* __restrict__ z, const float* __restrict__ Wl2h,
            const float* __restrict__ bl2h, float* __restrict__ ws)
{
    if (blockIdx.x == 0)
        ((unsigned*)(ws + WS_E))[threadIdx.x] = 0u;   // flags[0..255]
    const int t  = threadIdx.x;
    const int jl = t & 15, b = t >> 4;
    const int j  = blockIdx.x * 16 + jl;
    float acc = 0.f;
    #pragma unroll 4
    for (int k = 0; k < H; ++k)
        acc += z[b * H + k] * Wl2h[(size_t)k * H + j];
    acc += bl2h[j];

    const unsigned realLsb[3] = { 1u, 0u, 1u };
    const int preh[3][3] = { { 1, 0, -1 },
                             { -1, 0, 1 },
                             { 0, -1, 1 } };
    const unsigned preA1[3] = { 0u, 1u, 0u };
    #pragma unroll
    for (int l = 0; l < 3; ++l)
        #pragma unroll
        for (int p = 0; p < 3; ++p) {
            float v = (preh[l][p] < 0) ? stampf(acc, realLsb[l])
                                       : __uint_as_float((unsigned)preh[l][p]);
            ws[WS_STATE(l, p) + j * 16 + b] = v;
        }
    #pragma unroll
    for (int p = 0; p < 3; ++p)
        ws[WS_A1(p) + j * 16 + b] = __uint_as_float(preA1[p]);
}

// ---------------- persistent pipelined GRU + MLP decoder ----------------
// Regular (non-cooperative) launch: grid 224 x 1 block/CU (85 KB LDS) on 256 CUs
// -> co-resident by capacity; flag protocol needs only co-residency.
__global__ __launch_bounds__(512, 2)
void k_gru(const float* __restrict__ W_ih, const float* __restrict__ W_hh,
           const float* __restrict__ b_ih, const float* __restrict__ b_hh,
           const float* __restrict__ Wa1,  const float* __restrict__ ba1,
           const float* __restrict__ Wa2,  const float* __restrict__ ba2,
           float* __restrict__ ws)
{
    __shared__ float sx[10240];
    __shared__ float sh[10240];
    __shared__ float red[768];
    unsigned* flags = (unsigned*)(ws + WS_E);

    const int bid = blockIdx.x;
    const int tid = threadIdx.x;

    int job, jbase;
    if      (bid < 32)  { job = 0; jbase = bid * 16; }
    else if (bid < 96)  { job = 1; jbase = (bid - 32) * 8; }
    else if (bid < 160) { job = 2; jbase = (bid - 96) * 8; }
    else if (bid < 192) { job = 3; jbase = (bid - 160) * 16; }
    else                { job = 4; jbase = (bid - 192) * 16; }

    const int ks = tid & 31;
    const int qh = (tid >> 5) & 1;
    const int cs = tid >> 6;

    // ---- anti-dep poll set: consumers of the buffer this stage writes ----
    int rs0, rc0;
    if      (job == 0) { rs0 = 0;   rc0 = 96;  }
    else if (job == 1) { rs0 = 32;  rc0 = 128; }
    else if (job == 2) { rs0 = 96;  rc0 = 96;  }
    else if (job == 3) { rs0 = 192; rc0 = 32;  }
    else               { rs0 = 0;   rc0 = 0;   }
    int fidl[2];
    #pragma unroll
    for (int e = 0; e < 2; ++e) {
        int idx = (tid & 63) + e * 64;
        fidl[e] = (idx < rc0) ? rs0 + idx : bid;   // own flag trivially passes
    }

    // ---- one-time weight preload into registers ----
    float w[6][16];
    if (job <= 2) {
        const float* Wsrc;
        int colbase;
        if (job == 0) { Wsrc = W_hh; colbase = jbase + cs * 2; }
        else {
            Wsrc = ((cs & 1) ? W_hh : W_ih) + (size_t)job * H * TH3;
            colbase = jbase + (cs >> 1) * 2;
        }
        #pragma unroll
        for (int f = 0; f < 6; ++f) {
            int g = f >> 1, c = f & 1;
            #pragma unroll
            for (int kk = 0; kk < 16; ++kk)
                w[f][kk] = Wsrc[(size_t)(kk * 32 + ks) * TH3 + g * 512 + colbase + c];
        }
    } else {
        const float* base = (job == 3) ? Wa1 : Wa2;
        int colbase = jbase + cs * 2;
        #pragma unroll
        for (int f = 0; f < 2; ++f)
            #pragma unroll
            for (int kk = 0; kk < 16; ++kk)
                w[f][kk] = base[(size_t)(kk * 32 + ks) * H + colbase + f];
    }

    // ---- epilogue constants (biases + running h for own cols) ----
    float c_bi0 = 0, c_bi1 = 0, c_bi2 = 0, c_bh0 = 0, c_bh1 = 0, c_bh2 = 0;
    float hp = 0.f, c_ba = 0.f;
    if (job == 0 && tid < 256) {
        int b = tid & 15, j2 = tid >> 4, jc = jbase + j2;
        c_bi0 = b_ih[jc]; c_bi1 = b_ih[512 + jc]; c_bi2 = b_ih[1024 + jc];
        c_bh0 = b_hh[jc]; c_bh1 = b_hh[512 + jc]; c_bh2 = b_hh[1024 + jc];
        hp = ws[WS_STATE(0, 2) + jc * 16 + b];
    } else if ((job == 1 || job == 2) && tid < 128) {
        int b = tid & 15, j2 = tid >> 4, jc = jbase + j2;
        const float* bi  = b_ih + job * TH3;
        const float* bhh = b_hh + job * TH3;
        c_bi0 = bi[jc]; c_bi1 = bi[512 + jc]; c_bi2 = bi[1024 + jc];
        c_bh0 = bhh[jc]; c_bh1 = bhh[512 + jc]; c_bh2 = bhh[1024 + jc];
        hp = ws[WS_STATE(job, (job + 2) % 3) + jc * 16 + b];
    } else if (job == 3 && tid < 256) {
        c_ba = ba1[jbase + (tid >> 4)];
    } else if (job == 4 && tid < 256) {
        c_ba = ba2[jbase + (tid & 15)];
    }

    const int k0 = tid >> 2;          // staging: first k row
    const int q4 = (tid & 3) * 4;     // staging: float offset within row
    const bool b0 = (ks & 1), b1 = (ks & 2), b3 = (ks & 8), b4 = (ks & 16);

    for (int s = 0; s < 100; ++s) {
        const int rp = (s + 2) % 3, wp = s % 3;
        const int act = (s >= job && s <= 95 + job);

        if (act) {
            const unsigned expb = (unsigned)((s + 1) & 1);   // == (s-1)&1

            // ---- anti-dep poll (wave 0, concurrent with other waves' staging) ----
            if (tid < 64 && s >= 2) {
                unsigned lim = (unsigned)(s - 1);
                for (;;) {
                    unsigned v0, v1;
                    ld_coh_u32x2(&flags[fidl[0]], &flags[fidl[1]], v0, v1);
                    int ok = (v0 >= lim) && (v1 >= lim);
                    if (__all(ok)) break;
                    __builtin_amdgcn_s_sleep(1);
                }
            }

            // ---- fused detect+stage: speculative coherent load + LSB check ----
            if (job == 1 || job == 2) {
                const float* sA = ws + WS_STATE(job - 1, rp);
                const float* sB = ws + WS_STATE(job, rp);
                float4 xa, xb, xc, xd, ha, hb, hc, hd;
                for (;;) {
                    ld_coh8(sA + 4 * tid, sA + 4 * (tid + 512),
                            sA + 4 * (tid + 1024), sA + 4 * (tid + 1536),
                            sB + 4 * tid, sB + 4 * (tid + 512),
                            sB + 4 * (tid + 1024), sB + 4 * (tid + 1536),
                            xa, xb, xc, xd, ha, hb, hc, hd);
                    int ok = lsb4ok(xa, expb) & lsb4ok(xb, expb) &
                             lsb4ok(xc, expb) & lsb4ok(xd, expb) &
                             lsb4ok(ha, expb) & lsb4ok(hb, expb) &
                             lsb4ok(hc, expb) & lsb4ok(hd, expb);
                    if (__all(ok)) break;
                    __builtin_amdgcn_s_sleep(1);
                }
                *(float4*)&sx[(k0      ) * 20 + q4] = xa;
                *(float4*)&sx[(k0 + 128) * 20 + q4] = xb;
                *(float4*)&sx[(k0 + 256) * 20 + q4] = xc;
                *(float4*)&sx[(k0 + 384) * 20 + q4] = xd;
                *(float4*)&sh[(k0      ) * 20 + q4] = ha;
                *(float4*)&sh[(k0 + 128) * 20 + q4] = hb;
                *(float4*)&sh[(k0 + 256) * 20 + q4] = hc;
                *(float4*)&sh[(k0 + 384) * 20 + q4] = hd;
            } else {
                const float* sA = (job == 0) ? (ws + WS_STATE(0, rp))
                                : (job == 3) ? (ws + WS_STATE(2, rp))
                                             : (ws + WS_A1(rp));
                float4 xa, xb, xc, xd;
                for (;;) {
                    ld_coh4(sA + 4 * tid, sA + 4 * (tid + 512),
                            sA + 4 * (tid + 1024), sA + 4 * (tid + 1536),
                            xa, xb, xc, xd);
                    int ok = lsb4ok(xa, expb) & lsb4ok(xb, expb) &
                             lsb4ok(xc, expb) & lsb4ok(xd, expb);
                    if (__all(ok)) break;
                    __builtin_amdgcn_s_sleep(1);
                }
                *(float4*)&sx[(k0      ) * 20 + q4] = xa;
                *(float4*)&sx[(k0 + 128) * 20 + q4] = xb;
                *(float4*)&sx[(k0 + 256) * 20 + q4] = xc;
                *(float4*)&sx[(k0 + 384) * 20 + q4] = xd;
            }
            __syncthreads();

            // ---- register-weight dot products ----
            const int rowoff = 8 * qh;
            if (job <= 2) {
                const float* arr = (job != 0 && (cs & 1)) ? sh : sx;
                float acc[6][8];
                #pragma unroll
                for (int f = 0; f < 6; ++f)
                    #pragma unroll
                    for (int i = 0; i < 8; ++i) acc[f][i] = 0.f;
                #pragma unroll
                for (int kk = 0; kk < 16; ++kk) {
                    const float* p = arr + (kk * 32 + ks) * 20 + rowoff;
                    float4 v0 = *(const float4*)p;
                    float4 v1 = *(const float4*)(p + 4);
                    #pragma unroll
                    for (int f = 0; f < 6; ++f) {
                        float wv = w[f][kk];
                        acc[f][0] += wv * v0.x; acc[f][1] += wv * v0.y;
                        acc[f][2] += wv * v0.z; acc[f][3] += wv * v0.w;
                        acc[f][4] += wv * v1.x; acc[f][5] += wv * v1.y;
                        acc[f][6] += wv * v1.z; acc[f][7] += wv * v1.w;
                    }
                }
                // ---- reduce-scatter over ks ----
                float a[6];
                #pragma unroll
                for (int f = 0; f < 6; ++f) {
                    float t[4];
                    #pragma unroll
                    for (int j = 0; j < 4; ++j) {
                        float give = b0 ? acc[f][j] : acc[f][j + 4];
                        float recv = dppmov<DPP_XOR1>(give);
                        float keep = b0 ? acc[f][j + 4] : acc[f][j];
                        t[j] = keep + recv;
                    }
                    float u[2];
                    #pragma unroll
                    for (int j = 0; j < 2; ++j) {
                        float give = b1 ? t[j] : t[j + 2];
                        float recv = dppmov<DPP_XOR2>(give);
                        float keep = b1 ? t[j + 2] : t[j];
                        u[j] = keep + recv;
                    }
                    {
                        float give = b3 ? u[0] : u[1];
                        float recv = dppmov<DPP_XOR8>(give);
                        float keep = b3 ? u[1] : u[0];
                        a[f] = keep + recv;
                    }
                }
                #pragma unroll
                for (int f = 0; f < 6; ++f) a[f] += swzf<SWZ_XOR4>(a[f]);
                float r[3];
                #pragma unroll
                for (int i = 0; i < 3; ++i) {
                    float give = b4 ? a[i] : a[i + 3];
                    float recv = swzf<SWZ_XOR16>(give);
                    float keep = b4 ? a[i + 3] : a[i];
                    r[i] = keep + recv;
                }
                if (!(ks & 4)) {
                    int bl = ((ks & 1) << 2) | (ks & 2) | ((ks >> 3) & 1);
                    int bb = qh * 8 + bl;
                    int fb3 = ((ks >> 4) & 1) * 3;
                    #pragma unroll
                    for (int i = 0; i < 3; ++i) {
                        int f = fb3 + i, g = f >> 1, c = f & 1;
                        int idx = (job == 0)
                            ? g * 256 + (cs * 2 + c) * 16 + bb
                            : (cs & 1) * 384 + g * 128 + ((cs >> 1) * 2 + c) * 16 + bb;
                        red[idx] = r[i];
                    }
                }
            } else {
                float acc[2][8];
                #pragma unroll
                for (int f = 0; f < 2; ++f)
                    #pragma unroll
                    for (int i = 0; i < 8; ++i) acc[f][i] = 0.f;
                #pragma unroll
                for (int kk = 0; kk < 16; ++kk) {
                    const float* p = sx + (kk * 32 + ks) * 20 + rowoff;
                    float4 v0 = *(const float4*)p;
                    float4 v1 = *(const float4*)(p + 4);
                    #pragma unroll
                    for (int f = 0; f < 2; ++f) {
                        float wv = w[f][kk];
                        acc[f][0] += wv * v0.x; acc[f][1] += wv * v0.y;
                        acc[f][2] += wv * v0.z; acc[f][3] += wv * v0.w;
                        acc[f][4] += wv * v1.x; acc[f][5] += wv * v1.y;
                        acc[f][6] += wv * v1.z; acc[f][7] += wv * v1.w;
                    }
                }
                float a[2];
                #pragma unroll
                for (int f = 0; f < 2; ++f) {
                    float t[4];
                    #pragma unroll
                    for (int j = 0; j < 4; ++j) {
                        float give = b0 ? acc[f][j] : acc[f][j + 4];
                        float recv = dppmov<DPP_XOR1>(give);
                        float keep = b0 ? acc[f][j + 4] : acc[f][j];
                        t[j] = keep + recv;
                    }
                    float u[2];
                    #pragma unroll
                    for (int j = 0; j < 2; ++j) {
                        float give = b1 ? t[j] : t[j + 2];
                        float recv = dppmov<DPP_XOR2>(give);
                        float keep = b1 ? t[j + 2] : t[j];
                        u[j] = keep + recv;
                    }
                    float give = b3 ? u[0] : u[1];
                    float recv = dppmov<DPP_XOR8>(give);
                    float keep = b3 ? u[1] : u[0];
                    a[f] = keep + recv;
                }
                a[0] += swzf<SWZ_XOR4>(a[0]);
                a[1] += swzf<SWZ_XOR4>(a[1]);
                float give = b4 ? a[0] : a[1];
                float recv = swzf<SWZ_XOR16>(give);
                float keep = b4 ? a[1] : a[0];
                float r0 = keep + recv;
                if (!(ks & 4)) {
                    int bl = ((ks & 1) << 2) | (ks & 2) | ((ks >> 3) & 1);
                    int bb = qh * 8 + bl;
                    int fb = (ks >> 4) & 1;
                    red[(cs * 2 + fb) * 16 + bb] = r0;
                }
            }
            __syncthreads();

            // ---- epilogue (LSB-stamped coherent stores for cross-block state) ----
            const unsigned myb = (unsigned)(s & 1);
            if (job == 0) {
                if (tid < 256) {
                    int b = tid & 15, j2 = tid >> 4, jc = jbase + j2;
                    float g0 = red[       j2 * 16 + b];
                    float g1 = red[256  + j2 * 16 + b];
                    float g2 = red[512  + j2 * 16 + b];
                    float r  = sigm_(c_bi0 + g0 + c_bh0);
                    float zg = sigm_(c_bi1 + g1 + c_bh1);
                    float n  = tanhf(c_bi2 + r * (g2 + c_bh2));
                    float hn = (1.f - zg) * n + zg * hp;
                    hp = hn;
                    st_coh1(&ws[WS_STATE(0, wp) + jc * 16 + b], stampf(hn, myb));
                }
            } else if (job <= 2) {
                if (tid < 128) {
                    int b = tid & 15, j2 = tid >> 4, jc = jbase + j2;
                    float gi0 = red[        j2 * 16 + b], gh0 = red[384 +       j2 * 16 + b];
                    float gi1 = red[128  +  j2 * 16 + b], gh1 = red[384 + 128 + j2 * 16 + b];
                    float gi2 = red[256  +  j2 * 16 + b], gh2 = red[384 + 256 + j2 * 16 + b];
                    float r  = sigm_(gi0 + c_bi0 + gh0 + c_bh0);
                    float zg = sigm_(gi1 + c_bi1 + gh1 + c_bh1);
                    float n  = tanhf(gi2 + c_bi2 + r * (gh2 + c_bh2));
                    float hn = (1.f - zg) * n + zg * hp;
                    hp = hn;
                    st_coh1(&ws[WS_STATE(job, wp) + jc * 16 + b], stampf(hn, myb));
                }
            } else if (job == 3) {
                if (tid < 256) {
                    int b = tid & 15, j2 = tid >> 4, jc = jbase + j2;
                    float v = red[j2 * 16 + b] + c_ba;
                    st_coh1(&ws[WS_A1(wp) + jc * 16 + b], stampf(fmaxf(v, 0.f), myb));
                }
            } else {
                if (tid < 256) {
                    int j2 = tid & 15, b = tid >> 4, jc = jbase + j2;
                    float v = red[j2 * 16 + b] + c_ba;
                    ws[WS_ATOMS + ((size_t)(s - 4) * 16 + b) * H + jc] = v;
                }
            }
        }

        // ---- post completion flag (anti-dep bookkeeping, off critical path) ----
        vm_drain();
        __syncthreads();
        if (tid == 0) st_coh_u32(&flags[bid], (unsigned)(s + 1));
    }
}

// ---------------- argmax over logits (first-max-wins) ----------------
extern "C" __global__ __launch_bounds__(256)
void k_argmax(const float* __restrict__ ws, float* __restrict__ out)
{
    const int t = blockIdx.x;                  // 0..95
    const int wv = threadIdx.x >> 6, lane = threadIdx.x & 63;
    for (int b = wv; b < 16; b += 4) {
        const float* row = ws + WS_ATOMS + ((size_t)t * 16 + b) * H;
        float mx = -3.4028235e38f; int mi = 0;
        #pragma unroll
        for (int c = 0; c < 8; ++c) {
            int idx = lane + c * 64;
            float v = row[idx];
            if (v > mx) { mx = v; mi = idx; }
        }
        #pragma unroll
        for (int off = 32; off >= 1; off >>= 1) {
            float omx = __shfl_down(mx, off);
            int   omi = __shfl_down(mi, off);
            if (omx > mx || (omx == mx && omi < mi)) { mx = omx; mi = omi; }
        }
        if (lane == 0) out[b * 96 + t] = (float)mi;
    }
}

// ---------------- e_i / e_j = atoms @ Wb1 halves, tiled (16 rows reuse) -------
extern "C" __global__ __launch_bounds__(256)
void k_eij(const float* __restrict__ Wb1, const float* __restrict__ bb1,
           float* __restrict__ ws)
{
    __shared__ float aT[8192];                 // [k][b16], 32 KB
    const int bid = blockIdx.x;
    const int t = bid >> 4, m = (bid >> 3) & 1, ct = bid & 7;
    const int tid = threadIdx.x;
    const float* atoms = ws + WS_ATOMS;
    for (int f = tid; f < 2048; f += 256) {    // transpose-stage A tile
        int b = f >> 7, kq = f & 127;
        float4 v = ((const float4*)(atoms + ((size_t)(t * 16 + b)) * H))[kq];
        aT[(kq * 4 + 0) * 16 + b] = v.x;
        aT[(kq * 4 + 1) * 16 + b] = v.y;
        aT[(kq * 4 + 2) * 16 + b] = v.z;
        aT[(kq * 4 + 3) * 16 + b] = v.w;
    }
    __syncthreads();
    const int c = tid & 63, rq = tid >> 6;
    const int col = ct * 64 + c;
    const float* Wp = Wb1 + (size_t)m * H * H + col;
    float a0 = 0, a1 = 0, a2 = 0, a3 = 0;
    #pragma unroll 8
    for (int k = 0; k < 512; ++k) {
        float  wv = Wp[(size_t)k * H];
        float4 av = *(const float4*)&aT[k * 16 + rq * 4];
        a0 += av.x * wv; a1 += av.y * wv; a2 += av.z * wv; a3 += av.w * wv;
    }
    float bb = (m == 0) ? bb1[col] : 0.f;
    a0 += bb; a1 += bb; a2 += bb; a3 += bb;
    float* eb = ws + WS_E + (size_t)(m * 16) * 96 * H;
    eb[((size_t)(rq * 4 + 0) * 96 + t) * H + col] = a0;
    eb[((size_t)(rq * 4 + 1) * 96 + t) * H + col] = a1;
    eb[((size_t)(rq * 4 + 2) * 96 + t) * H + col] = a2;
    eb[((size_t)(rq * 4 + 3) * 96 + t) * H + col] = a3;
}

// ---------------- fused edge MLP: relu(e_i + e_j) @ Wb2 + bb2, diag zeroed ----
// Wb2 (8 KB) preloaded into LDS -> broadcast ds_reads instead of uniform VMEM.
extern "C" __global__ __launch_bounds__(256)
void k_edge(const float* __restrict__ Wb2, const float* __restrict__ bb2,
            const float* __restrict__ ws, float* __restrict__ out)
{
    __shared__ float ls[32][260];
    __shared__ float wsm[2048];
    const int bid = blockIdx.x;                // b*36 + it*6 + jt
    const int b = bid / 36, r6 = bid % 36, it = r6 / 6, jt = r6 % 6;
    const int tid = threadIdx.x;
    const int ip = tid & 15, jp = tid >> 4;
    float acc0 = 0, acc1 = 0, acc2 = 0, acc3 = 0;

    for (int f = tid; f < 2048; f += 256)      // Wb2 -> LDS (one-time)
        wsm[f] = Wb2[f];

    for (int ph = 0; ph < 2; ++ph) {
        __syncthreads();
        for (int f = tid; f < 2048; f += 256) {
            int r = f >> 6, c4 = f & 63;
            const float* src = (r < 16)
                ? ws + WS_E + ((size_t)b * 96 + it * 16 + r) * H
                : ws + WS_E + ((size_t)(16 + b) * 96 + jt * 16 + (r - 16)) * H;
            float4 v = *(const float4*)(src + ph * 256 + c4 * 4);
            *(float4*)&ls[r][c4 * 4] = v;
        }
        __syncthreads();
        const float* wb = &wsm[ph * 1024];
        #pragma unroll 2
        for (int hh = 0; hh < 256; hh += 4) {
            float4 ei = *(const float4*)&ls[ip][hh];
            float4 ej = *(const float4*)&ls[16 + jp][hh];
            float4 w0 = *(const float4*)(wb + (size_t)hh * 4);
            float4 w1 = *(const float4*)(wb + (size_t)hh * 4 + 4);
            float4 w2 = *(const float4*)(wb + (size_t)hh * 4 + 8);
            float4 w3 = *(const float4*)(wb + (size_t)hh * 4 + 12);
            float v;
            v = fmaxf(ei.x + ej.x, 0.f); acc0 += v * w0.x; acc1 += v * w0.y; acc2 += v * w0.z; acc3 += v * w0.w;
            v = fmaxf(ei.y + ej.y, 0.f); acc0 += v * w1.x; acc1 += v * w1.y; acc2 += v * w1.z; acc3 += v * w1.w;
            v = fmaxf(ei.z + ej.z, 0.f); acc0 += v * w2.x; acc1 += v * w2.y; acc2 += v * w2.z; acc3 += v * w2.w;
            v = fmaxf(ei.w + ej.w, 0.f); acc0 += v * w3.x; acc1 += v * w3.y; acc2 += v * w3.z; acc3 += v * w3.w;
        }
    }
    const int i = it * 16 + ip, j = jt * 16 + jp;
    float4 o;
    if (i == j) { o.x = 0.f; o.y = 0.f; o.z = 0.f; o.w = 0.f; }
    else { o.x = acc0 + bb2[0]; o.y = acc1 + bb2[1]; o.z = acc2 + bb2[2]; o.w = acc3 + bb2[3]; }
    *(float4*)(out + 1536 + (((size_t)b * 96 + i) * 96 + j) * 4) = o;
}

// ---------------- host ----------------
extern "C" void kernel_launch(void* const* d_in, const int* in_sizes, int n_in,
                              void* d_out, int out_size, void* d_ws, size_t ws_size,
                              hipStream_t stream)
{
    const float* z    = (const float*)d_in[0];
    const float* Wl2h = (const float*)d_in[1];
    const float* bl2h = (const float*)d_in[2];
    const float* W_ih = (const float*)d_in[3];
    const float* W_hh = (const float*)d_in[4];
    const float* b_ih = (const float*)d_in[5];
    const float* b_hh = (const float*)d_in[6];
    const float* Wa1  = (const float*)d_in[7];
    const float* ba1  = (const float*)d_in[8];
    const float* Wa2  = (const float*)d_in[9];
    const float* ba2  = (const float*)d_in[10];
    const float* Wb1  = (const float*)d_in[11];
    const float* bb1  = (const float*)d_in[12];
    const float* Wb2  = (const float*)d_in[13];
    const float* bb2  = (const float*)d_in[14];
    float* out = (float*)d_out;
    float* ws  = (float*)d_ws;

    hipLaunchKernelGGL(k_init, dim3(32), dim3(256), 0, stream, z, Wl2h, bl2h, ws);

    // regular launch: grid 224 (1 block/CU by LDS) is co-resident by capacity
    hipLaunchKernelGGL(k_gru, dim3(GRID), dim3(512), 0, stream,
                       W_ih, W_hh, b_ih, b_hh, Wa1, ba1, Wa2, ba2, ws);

    hipLaunchKernelGGL(k_argmax, dim3(96), dim3(256), 0, stream, ws, out);
    hipLaunchKernelGGL(k_eij, dim3(1536), dim3(256), 0, stream, Wb1, bb1, ws);
    hipLaunchKernelGGL(k_edge, dim3(576), dim3(256), 0, stream, Wb2, bb2, ws, out);
}